// Round 15
// baseline (329.686 us; speedup 1.0000x reference)
//
#include <hip/hip_runtime.h>
#include <math.h>

// SeesawLoss, one-hot specialization, s-gather-free:
//   s[i,j] = min(a_j/a_i, 1) with a_k = counts[k]^p  (ties -> 1, matches strict >)
//   denom_i = (1/a_i)*sum_{a_j<a_i} a_j e_j + sum_{a_j>=a_i} e_j   (j=i lands in part2, coef 1)
//   a[] is recovered from s's max-count row i* (fewest ==1.0f entries, integer-exact test).
//   Seesaw then reads ONLY the logits stream + a 4920B LDS vector: no per-wave L2/L3
//   gather, no dependent address chain beyond labels[n] -> a_lds[li] (LDS broadcast).
// History: r5 117us (fused, gather chain); r9/r14 split ~85-90us regardless of load
// width (float2 vs float4 null) -> dependent s-gather cluster is the ~57us cost vs
// label_kernel's 28us on the same 161MB. This round removes it.

constexpr int N_ROWS = 32768;
constexpr int C_CLS  = 1230;
constexpr int C2     = C_CLS / 2;        // 615 float2 per row
constexpr int C4     = C_CLS / 4;        // 307 full float4 (+ float2 tail at idx 614)
constexpr int BLK    = 256;
constexpr int WPB    = BLK / 64;         // 4 rows per block
constexpr unsigned TOT  = (unsigned)N_ROWS * (unsigned)C_CLS;  // 40,304,640
constexpr unsigned TOT4 = TOT / 4;                             // 10,076,160
constexpr float EPS_F = 1e-6f;

// ---- Pass 1: labels from one-hot targets (flat float4 stream, ~28us) -------
__global__ __launch_bounds__(BLK) void label_kernel(
    const float* __restrict__ targets, int* __restrict__ labels)
{
    const float4* t4 = reinterpret_cast<const float4*>(targets);
    const unsigned stride = gridDim.x * BLK;
    for (unsigned i = blockIdx.x * BLK + threadIdx.x; i < TOT4; i += stride) {
        const float4 v = t4[i];
        if (v.x > 0.5f || v.y > 0.5f || v.z > 0.5f || v.w > 0.5f) {  // rare
            const unsigned g = i * 4u;
            #pragma unroll
            for (int e = 0; e < 4; ++e) {
                const float val = (e == 0) ? v.x : (e == 1) ? v.y : (e == 2) ? v.z : v.w;
                if (val > 0.5f) {
                    const unsigned gg = g + (unsigned)e;
                    const unsigned n  = gg / (unsigned)C_CLS;
                    const unsigned c  = gg - n * (unsigned)C_CLS;
                    labels[n] = (int)c;
                }
            }
        }
    }
}

// ---- Pass 2a: per-row count of ==1.0f entries in s (wave per row) ----------
__global__ __launch_bounds__(BLK) void rowones_kernel(
    const float* __restrict__ s, int* __restrict__ rowcnt)
{
    const int wid  = (blockIdx.x * BLK + threadIdx.x) >> 6;   // global wave id = row
    const int lane = threadIdx.x & 63;
    if (wid >= C_CLS) return;
    const float2* srow2 = reinterpret_cast<const float2*>(s + (size_t)wid * C_CLS);
    int cnt = 0;
    #pragma unroll
    for (int it = 0; it < 10; ++it) {             // 615 float2, lane+it*64 < 615
        const int k = lane + it * 64;
        if (k < C2) {
            const float2 v = srow2[k];
            cnt += (v.x == 1.0f) + (v.y == 1.0f);
        }
    }
    #pragma unroll
    for (int off = 32; off > 0; off >>= 1) cnt += __shfl_xor(cnt, off);
    if (lane == 0) rowcnt[wid] = cnt;
}

// ---- Pass 2b: i* = argmin rowcnt (max-count class row), integer-exact ------
__global__ __launch_bounds__(256) void argmin_kernel(
    const int* __restrict__ rowcnt, int* __restrict__ istar)
{
    int best = 0x7fffffff;
    for (int i = threadIdx.x; i < C_CLS; i += 256)
        best = min(best, (rowcnt[i] << 11) | i);   // cnt<=1230 fits; ties -> lowest idx
    #pragma unroll
    for (int off = 32; off > 0; off >>= 1) best = min(best, __shfl_xor(best, off));
    __shared__ int red[4];
    if ((threadIdx.x & 63) == 0) red[threadIdx.x >> 6] = best;
    __syncthreads();
    if (threadIdx.x == 0)
        istar[0] = min(min(red[0], red[1]), min(red[2], red[3])) & 2047;
}

// ---- Pass 3: per-row loss, wave-per-row, pure logits stream + LDS a[] ------
__global__ __launch_bounds__(BLK) void seesaw_row_kernel(
    const float* __restrict__ logits,
    const float* __restrict__ s,
    const int*   __restrict__ labels,
    const int*   __restrict__ istar_p,
    float* __restrict__ row_loss)
{
    __shared__ float a_lds[1232];                 // 1230 + 2 zero pad (float4-safe)
    const int t    = threadIdx.x;
    const int lane = t & 63;
    const int wv   = t >> 6;
    const int n    = blockIdx.x * WPB + wv;

    // stage a[] = s[i*,:] (float2: always 8B-aligned), pad to zeros
    const int istar = istar_p[0];
    const float2* arow2 = reinterpret_cast<const float2*>(s + (size_t)istar * C_CLS);
    float2* a2 = reinterpret_cast<float2*>(a_lds);
    for (int k = t; k < 616; k += BLK)
        a2[k] = (k < C2) ? arow2[k] : make_float2(0.0f, 0.0f);
    __syncthreads();

    // label -> tiny LDS lookup (no global gather chain)
    const int li = __builtin_amdgcn_readfirstlane(labels[n]);
    const float r_i = a_lds[li];

    // logits row: float4 stream, exact float2 tail, -INF fills (e=0 self-mask)
    const float* lrow = logits + (size_t)n * C_CLS;
    const float4* lrow4 = reinterpret_cast<const float4*>(lrow);
    const float2* lrow2 = reinterpret_cast<const float2*>(lrow);
    float4 l[5];
    #pragma unroll
    for (int it = 0; it < 5; ++it) {
        const int idx4 = lane + it * 64;
        if (idx4 < C4) {
            l[it] = lrow4[idx4];
        } else if (idx4 == C4) {
            const float2 tl = lrow2[C2 - 1];      // elems 1228,1229
            l[it] = make_float4(tl.x, tl.y, -INFINITY, -INFINITY);
        } else {
            l[it] = make_float4(-INFINITY, -INFINITY, -INFINITY, -INFINITY);
        }
    }
    const float lval = lrow[li];                  // own-row gather, L1/L2-hot

    // row max
    float lmax = -INFINITY;
    #pragma unroll
    for (int it = 0; it < 5; ++it)
        lmax = fmaxf(lmax, fmaxf(fmaxf(l[it].x, l[it].y), fmaxf(l[it].z, l[it].w)));
    #pragma unroll
    for (int off = 32; off > 0; off >>= 1)
        lmax = fmaxf(lmax, __shfl_xor(lmax, off));
    const float m = lmax;

    // masked sums: p1 = sum_{a<r} a*e, p2 = sum_{a>=r} e
    const float4* a4 = reinterpret_cast<const float4*>(a_lds);
    float p1 = 0.0f, p2 = 0.0f;
    #pragma unroll
    for (int it = 0; it < 5; ++it) {
        const int idx4 = lane + it * 64;
        if (idx4 <= C4) {                          // a4[307] safe (zero-padded)
            const float4 av = a4[idx4];
            const float ex = __expf(l[it].x - m);
            const float ey = __expf(l[it].y - m);
            const float ez = __expf(l[it].z - m);
            const float ew = __expf(l[it].w - m);
            p1 += (av.x < r_i) ? av.x * ex : 0.0f;  p2 += (av.x < r_i) ? 0.0f : ex;
            p1 += (av.y < r_i) ? av.y * ey : 0.0f;  p2 += (av.y < r_i) ? 0.0f : ey;
            p1 += (av.z < r_i) ? av.z * ez : 0.0f;  p2 += (av.z < r_i) ? 0.0f : ez;
            p1 += (av.w < r_i) ? av.w * ew : 0.0f;  p2 += (av.w < r_i) ? 0.0f : ew;
        }
        // idx4 > C4: l=-INF -> e=0, a=0 -> contribution 0 either way: skip
    }
    #pragma unroll
    for (int off = 32; off > 0; off >>= 1) {
        p1 += __shfl_xor(p1, off);
        p2 += __shfl_xor(p2, off);
    }

    if (lane == 0) {
        const float denom = p1 / r_i + p2;        // j=li sits in p2 with coef 1 == s_ii
        row_loss[n] = __logf(denom + EPS_F) - (lval - m);
    }
}

// ---- Deterministic mean (double accum), one 1024-thread block --------------
__global__ __launch_bounds__(1024) void reduce_mean_kernel(
    const float* __restrict__ row_loss, float* __restrict__ out)
{
    const int t    = threadIdx.x;
    const int lane = t & 63;
    const int wv   = t >> 6;                    // 16 waves
    const float4* rl4 = reinterpret_cast<const float4*>(row_loss);
    constexpr int N4 = N_ROWS / 4;
    double acc = 0.0;
    #pragma unroll 8
    for (int i = t; i < N4; i += 1024) {
        const float4 v = rl4[i];
        acc += (double)v.x + (double)v.y + (double)v.z + (double)v.w;
    }
    #pragma unroll
    for (int off = 32; off > 0; off >>= 1)
        acc += __shfl_down(acc, off);
    __shared__ double red[16];
    if (lane == 0) red[wv] = acc;
    __syncthreads();
    if (t == 0) {
        double tot = 0.0;
        #pragma unroll
        for (int w = 0; w < 16; ++w) tot += red[w];
        out[0] = (float)(tot / (double)N_ROWS);
    }
}

extern "C" void kernel_launch(void* const* d_in, const int* in_sizes, int n_in,
                              void* d_out, int out_size, void* d_ws, size_t ws_size,
                              hipStream_t stream) {
    const float* logits  = (const float*)d_in[0];   // [N, C]
    const float* targets = (const float*)d_in[1];   // [N, C] one-hot f32
    const float* s       = (const float*)d_in[2];   // [C, C]
    float* out = (float*)d_out;                     // scalar f32

    char* ws = (char*)d_ws;
    int*   labels   = (int*)  (ws);                 // 128 KiB
    float* row_loss = (float*)(ws + 131072);        // 128 KiB
    int*   rowcnt   = (int*)  (ws + 262144);        // 4920 B
    int*   istar    = (int*)  (ws + 267072);        // 4 B

    label_kernel  <<<2048, BLK, 0, stream>>>(targets, labels);
    rowones_kernel<<<(C_CLS + WPB - 1) / WPB, BLK, 0, stream>>>(s, rowcnt);
    argmin_kernel <<<1, 256, 0, stream>>>(rowcnt, istar);
    seesaw_row_kernel<<<N_ROWS / WPB, BLK, 0, stream>>>(logits, s, labels, istar, row_loss);
    reduce_mean_kernel<<<1, 1024, 0, stream>>>(row_loss, out);
}